// Round 4
// baseline (168.411 us; speedup 1.0000x reference)
//
#include <hip/hip_runtime.h>
#include <math.h>

// AFM forward: out[b] = linear(b) + softmax-weighted pair-interaction projection.
// B=4096, F=26, d=64, P=325 pairs, af=64.
//
// R4: one 128-thread block (2 waves) per batch row, grid=B=4096 blocks.
// R3 post-mortem: grid shape capped residency at 16 waves/CU (occupancy 33%,
// all pipes ~1/3 busy -> latency-filling starved). Splitting each row across
// 2 waves doubles resident waves (up to 32/CU) and halves per-wave VALU/LDS
// work. __syncthreads now couples only 2 waves. Pipeline stays f16 MFMA.

#define NF 26
#define NP 325
#define NPP 336          // padded to 21 m-tiles of 16
#define NMT 21
#define ED 64
#define AF 64
#define NDENSE 13
#define BLOCK 128        // 2 waves, one row per block
#define ESTRIDE 72       // f16 elems per emb row: 144 B (16B-aligned)

typedef __attribute__((ext_vector_type(8))) _Float16 half8;
typedef __attribute__((ext_vector_type(4))) _Float16 half4;
typedef __attribute__((ext_vector_type(4))) float f32x4;

__global__ void prep_kernel(const float* __restrict__ W1,
                            _Float16* __restrict__ w1t,        // [64][64] = W1^T, f16
                            unsigned short* __restrict__ tab)  // [336] i | j<<8
{
    int t = threadIdx.x;
    for (int idx = t; idx < ED * AF; idx += 256) {
        int d = idx >> 6, a = idx & 63;       // W1 is [d][a]
        w1t[a * ED + d] = (_Float16)W1[idx];
    }
    if (t < NPP) {
        unsigned short v = 0;
        if (t < NP) {
            int rem = t, i = 0;
            while (rem >= NF - 1 - i) { rem -= NF - 1 - i; ++i; }
            v = (unsigned short)(i | ((i + 1 + rem) << 8));
        }
        tab[t] = v;
    }
}

__global__ __launch_bounds__(BLOCK, 8)
void afm_kernel(const int*   __restrict__ sparse,   // [B,26]
                const float* __restrict__ dense,    // [B,13]
                const float* __restrict__ etab,     // [V,64]
                const float* __restrict__ ltab,     // [V]
                const float* __restrict__ wdense,   // [13]
                const float* __restrict__ bias,     // [1]
                const float* __restrict__ b1,       // [64]
                const float* __restrict__ w2,       // [64]
                const float* __restrict__ proj,     // [64]
                const _Float16* __restrict__ w1t,   // [64][64] f16 (a-major)
                const unsigned short* __restrict__ tab, // [336]
                float*       __restrict__ out)      // [B]
{
    const int t    = threadIdx.x;
    const int wave = t >> 6;
    const int lane = t & 63;
    const int qd   = lane >> 4;     // quad 0..3
    const int ln   = lane & 15;
    const int r    = blockIdx.x;    // this block's batch row

    __shared__ alignas(16) _Float16 emb[NF][ESTRIDE];   // 3744 B
    __shared__ alignas(16) float    scores[NPP];        // 1344 B
    __shared__ alignas(16) float    partial[2][ED];     //  512 B

    // ---- B-fragment preload from global (L2-hot 8 KB): bfr[nt][kh] ----
    // B[k][n]: n = nt*16+ln, k = kh*32 + qd*8 + j  -> w1t[n][k]
    half8 bfr[4][2];
    #pragma unroll
    for (int nt = 0; nt < 4; ++nt)
        #pragma unroll
        for (int kh = 0; kh < 2; ++kh)
            bfr[nt][kh] = *(const half8*)(w1t + (nt * 16 + ln) * ED + kh * 32 + qd * 8);

    float b1v[4], w2v[4];
    #pragma unroll
    for (int nt = 0; nt < 4; ++nt) {
        b1v[nt] = b1[nt * 16 + ln];
        w2v[nt] = w2[nt * 16 + ln];
    }

    // ---- stage this row's 26 embeddings into LDS as f16 (both waves) ----
    const int* __restrict__ srow = sparse + r * NF;
    for (int task = t; task < NF * 16; task += BLOCK) {
        int f = task >> 4, q = task & 15;
        float4 v = *(const float4*)(etab + (size_t)srow[f] * ED + q * 4);
        half4 h = { (_Float16)v.x, (_Float16)v.y, (_Float16)v.z, (_Float16)v.w };
        *(half4*)(&emb[f][q * 4]) = h;
    }

    // ---- linear part (wave 0 registers only) ----
    float lin = 0.f;
    if (wave == 0) {
        if (lane < NF) {
            lin = ltab[srow[lane]];
        } else if (lane >= 32 && lane < 32 + NDENSE) {
            int k = lane - 32;
            lin = dense[r * NDENSE + k] * wdense[k];
        }
        #pragma unroll
        for (int off = 32; off >= 1; off >>= 1) lin += __shfl_xor(lin, off, 64);
        lin += bias[0];
    }

    __syncthreads();   // emb visible

    // ---- phase 1: pair-MLP logits via MFMA f16; wave w does mt = w, w+2,... ----
    for (int mt = wave; mt < NMT; mt += 2) {
        const int p0 = mt * 16 + ln;
        const unsigned pp = tab[p0];
        const int fi = pp & 0xff, fj = pp >> 8;

        // A[m=ln][k=qd*8+j] = emb[fi][k] * emb[fj][k], two K-halves
        half8 a0 = *(const half8*)(&emb[fi][qd * 8])      * *(const half8*)(&emb[fj][qd * 8]);
        half8 a1 = *(const half8*)(&emb[fi][32 + qd * 8]) * *(const half8*)(&emb[fj][32 + qd * 8]);

        float lg[4] = {0.f, 0.f, 0.f, 0.f};
        #pragma unroll
        for (int nt = 0; nt < 4; ++nt) {
            f32x4 acc = {0.f, 0.f, 0.f, 0.f};
            acc = __builtin_amdgcn_mfma_f32_16x16x32_f16(a0, bfr[nt][0], acc, 0, 0, 0);
            acc = __builtin_amdgcn_mfma_f32_16x16x32_f16(a1, bfr[nt][1], acc, 0, 0, 0);
            // C layout: col = ln (a), row = qd*4 + reg (pair)
            #pragma unroll
            for (int rr = 0; rr < 4; ++rr)
                lg[rr] = fmaf(fmaxf(acc[rr] + b1v[nt], 0.f), w2v[nt], lg[rr]);
        }
        #pragma unroll
        for (int off = 1; off <= 8; off <<= 1) {
            #pragma unroll
            for (int rr = 0; rr < 4; ++rr) lg[rr] += __shfl_xor(lg[rr], off, 64);
        }
        if (ln == 0) {
            const int pr = mt * 16 + qd * 4;
            float4 st;
            st.x = (pr + 0 < NP) ? lg[0] : -INFINITY;
            st.y = (pr + 1 < NP) ? lg[1] : -INFINITY;
            st.z = (pr + 2 < NP) ? lg[2] : -INFINITY;
            st.w = (pr + 3 < NP) ? lg[3] : -INFINITY;
            *(float4*)(&scores[pr]) = st;
        }
    }

    __syncthreads();   // logits visible

    // ---- softmax over 336 (pads -inf). Both waves compute redundantly,
    //      write disjoint chunks (wave0: k=0..2, wave1: k=3..5). ----
    float v[6];
    #pragma unroll
    for (int k = 0; k < 6; ++k) {
        int p = lane + (k << 6);
        v[k] = (p < NPP) ? scores[p] : -INFINITY;
    }
    float m = v[0];
    #pragma unroll
    for (int k = 1; k < 6; ++k) m = fmaxf(m, v[k]);
    #pragma unroll
    for (int off = 32; off >= 1; off >>= 1) m = fmaxf(m, __shfl_xor(m, off, 64));
    float e[6], esum = 0.f;
    #pragma unroll
    for (int k = 0; k < 6; ++k) { e[k] = __expf(v[k] - m); esum += e[k]; }
    #pragma unroll
    for (int off = 32; off >= 1; off >>= 1) esum += __shfl_xor(esum, off, 64);
    const float rinv = 1.0f / esum;
    __syncthreads();   // all raw-logit reads done before overwrite
    #pragma unroll
    for (int k = 0; k < 6; ++k) {
        if ((k >= wave * 3) && (k < wave * 3 + 3)) {
            int p = lane + (k << 6);
            if (p < NPP) scores[p] = e[k] * rinv;
        }
    }

    __syncthreads();   // normalized scores visible

    // ---- phase 3: att_out[d] = sum_p s_p * emb_i[d]*emb_j[d], packed f16.
    //      16 pairs/iter across both waves, 21 iters. ----
    const int dg  = lane & 7;                 // dim group: d = dg*8 .. dg*8+7
    const int sub = (wave << 3) + (lane >> 3);   // pair sub 0..15
    half8 acc8 = { (_Float16)0.f, (_Float16)0.f, (_Float16)0.f, (_Float16)0.f,
                   (_Float16)0.f, (_Float16)0.f, (_Float16)0.f, (_Float16)0.f };
    for (int it = 0; it < NPP / 16; ++it) {   // pads have score 0
        const int p = it * 16 + sub;
        const float s = scores[p];
        const unsigned pp = tab[p];
        const int fi = pp & 0xff, fj = pp >> 8;
        const _Float16 sh = (_Float16)s;
        half8 sv = { sh, sh, sh, sh, sh, sh, sh, sh };
        half8 x = *(const half8*)(&emb[fi][dg * 8]) * *(const half8*)(&emb[fj][dg * 8]);
        acc8 += sv * x;                       // v_pk_fma_f16
    }
    // reduce over this wave's sub lanes (bits 3..5)
    float av[8];
    #pragma unroll
    for (int i = 0; i < 8; ++i) av[i] = (float)acc8[i];
    #pragma unroll
    for (int off = 8; off <= 32; off <<= 1) {
        #pragma unroll
        for (int i = 0; i < 8; ++i) av[i] += __shfl_xor(av[i], off, 64);
    }
    if (lane < 8) {
        *(float4*)(&partial[wave][lane * 8])     = make_float4(av[0], av[1], av[2], av[3]);
        *(float4*)(&partial[wave][lane * 8 + 4]) = make_float4(av[4], av[5], av[6], av[7]);
    }
    __syncthreads();

    // ---- final: combine wave partials, project with p, add linear ----
    if (wave == 0 && lane < 8) {
        float4 s0 = *(const float4*)(&partial[0][lane * 8]);
        float4 s1 = *(const float4*)(&partial[0][lane * 8 + 4]);
        float4 t0 = *(const float4*)(&partial[1][lane * 8]);
        float4 t1 = *(const float4*)(&partial[1][lane * 8 + 4]);
        float4 pa = *(const float4*)(proj + lane * 8);
        float4 pb = *(const float4*)(proj + lane * 8 + 4);
        float part = (s0.x + t0.x) * pa.x + (s0.y + t0.y) * pa.y
                   + (s0.z + t0.z) * pa.z + (s0.w + t0.w) * pa.w
                   + (s1.x + t1.x) * pb.x + (s1.y + t1.y) * pb.y
                   + (s1.z + t1.z) * pb.z + (s1.w + t1.w) * pb.w;
        #pragma unroll
        for (int off = 1; off <= 4; off <<= 1) part += __shfl_xor(part, off, 64);
        if (lane == 0) out[r] = lin + part;
    }
}

extern "C" void kernel_launch(void* const* d_in, const int* in_sizes, int n_in,
                              void* d_out, int out_size, void* d_ws, size_t ws_size,
                              hipStream_t stream) {
    const int*   sparse = (const int*)  d_in[0];
    const float* dense  = (const float*)d_in[1];
    const float* etab   = (const float*)d_in[2];
    const float* ltab   = (const float*)d_in[3];
    const float* wdense = (const float*)d_in[4];
    const float* bias   = (const float*)d_in[5];
    const float* W1     = (const float*)d_in[6];
    const float* b1     = (const float*)d_in[7];
    const float* w2     = (const float*)d_in[8];
    const float* proj   = (const float*)d_in[9];
    float* outp = (float*)d_out;

    _Float16*       w1t = (_Float16*)d_ws;                          // 8192 B
    unsigned short* tab = (unsigned short*)((char*)d_ws + 8192);    //  672 B

    const int B = in_sizes[0] / NF;

    prep_kernel<<<dim3(1), dim3(256), 0, stream>>>(W1, w1t, tab);
    afm_kernel<<<dim3(B), dim3(BLOCK), 0, stream>>>(
        sparse, dense, etab, ltab, wdense, bias, b1, w2, proj, w1t, tab, outp);
    (void)n_in; (void)out_size; (void)ws_size;
}

// Round 5
// 135.209 us; speedup vs baseline: 1.2456x; 1.2456x over previous
//
#include <hip/hip_runtime.h>
#include <math.h>

// AFM forward: out[b] = linear(b) + softmax-weighted pair-interaction projection.
// B=4096, F=26, d=64, P=325 pairs, af=64.
//
// R5: R4 structure (one 128-thread block / 2 waves per row, grid=4096) with
// the register cap relaxed. R4 post-mortem: __launch_bounds__(128,8) forced
// VGPR=32 < the 32-VGPR bfr[] array alone -> B-fragments spilled to scratch,
// FETCH_SIZE 15->216 MB, WRITE 51 MB, kernel 47->86 us. launch_bounds(128,4)
// caps at ~128 VGPR; body needs ~48-56, which still permits 8 waves/SIMD.

#define NF 26
#define NP 325
#define NPP 336          // padded to 21 m-tiles of 16
#define NMT 21
#define ED 64
#define AF 64
#define NDENSE 13
#define BLOCK 128        // 2 waves, one row per block
#define ESTRIDE 72       // f16 elems per emb row: 144 B (16B-aligned)

typedef __attribute__((ext_vector_type(8))) _Float16 half8;
typedef __attribute__((ext_vector_type(4))) _Float16 half4;
typedef __attribute__((ext_vector_type(4))) float f32x4;

__global__ void prep_kernel(const float* __restrict__ W1,
                            _Float16* __restrict__ w1t,        // [64][64] = W1^T, f16
                            unsigned short* __restrict__ tab)  // [336] i | j<<8
{
    int t = threadIdx.x;
    for (int idx = t; idx < ED * AF; idx += 256) {
        int d = idx >> 6, a = idx & 63;       // W1 is [d][a]
        w1t[a * ED + d] = (_Float16)W1[idx];
    }
    if (t < NPP) {
        unsigned short v = 0;
        if (t < NP) {
            int rem = t, i = 0;
            while (rem >= NF - 1 - i) { rem -= NF - 1 - i; ++i; }
            v = (unsigned short)(i | ((i + 1 + rem) << 8));
        }
        tab[t] = v;
    }
}

__global__ __launch_bounds__(BLOCK, 4)   // VGPR cap ~128: room for bfr[] + accs, no spill
void afm_kernel(const int*   __restrict__ sparse,   // [B,26]
                const float* __restrict__ dense,    // [B,13]
                const float* __restrict__ etab,     // [V,64]
                const float* __restrict__ ltab,     // [V]
                const float* __restrict__ wdense,   // [13]
                const float* __restrict__ bias,     // [1]
                const float* __restrict__ b1,       // [64]
                const float* __restrict__ w2,       // [64]
                const float* __restrict__ proj,     // [64]
                const _Float16* __restrict__ w1t,   // [64][64] f16 (a-major)
                const unsigned short* __restrict__ tab, // [336]
                float*       __restrict__ out)      // [B]
{
    const int t    = threadIdx.x;
    const int wave = t >> 6;
    const int lane = t & 63;
    const int qd   = lane >> 4;     // quad 0..3
    const int ln   = lane & 15;
    const int r    = blockIdx.x;    // this block's batch row

    __shared__ alignas(16) _Float16 emb[NF][ESTRIDE];   // 3744 B
    __shared__ alignas(16) float    scores[NPP];        // 1344 B
    __shared__ alignas(16) float    partial[2][ED];     //  512 B

    // ---- B-fragment preload from global (L2-hot 8 KB): bfr[nt][kh] ----
    // B[k][n]: n = nt*16+ln, k = kh*32 + qd*8 + j  -> w1t[n][k]
    half8 bfr[4][2];
    #pragma unroll
    for (int nt = 0; nt < 4; ++nt)
        #pragma unroll
        for (int kh = 0; kh < 2; ++kh)
            bfr[nt][kh] = *(const half8*)(w1t + (nt * 16 + ln) * ED + kh * 32 + qd * 8);

    float b1v[4], w2v[4];
    #pragma unroll
    for (int nt = 0; nt < 4; ++nt) {
        b1v[nt] = b1[nt * 16 + ln];
        w2v[nt] = w2[nt * 16 + ln];
    }

    // ---- stage this row's 26 embeddings into LDS as f16 (both waves) ----
    const int* __restrict__ srow = sparse + r * NF;
    for (int task = t; task < NF * 16; task += BLOCK) {
        int f = task >> 4, q = task & 15;
        float4 v = *(const float4*)(etab + (size_t)srow[f] * ED + q * 4);
        half4 h = { (_Float16)v.x, (_Float16)v.y, (_Float16)v.z, (_Float16)v.w };
        *(half4*)(&emb[f][q * 4]) = h;
    }

    // ---- linear part (wave 0 registers only) ----
    float lin = 0.f;
    if (wave == 0) {
        if (lane < NF) {
            lin = ltab[srow[lane]];
        } else if (lane >= 32 && lane < 32 + NDENSE) {
            int k = lane - 32;
            lin = dense[r * NDENSE + k] * wdense[k];
        }
        #pragma unroll
        for (int off = 32; off >= 1; off >>= 1) lin += __shfl_xor(lin, off, 64);
        lin += bias[0];
    }

    __syncthreads();   // emb visible

    // ---- phase 1: pair-MLP logits via MFMA f16; wave w does mt = w, w+2,... ----
    for (int mt = wave; mt < NMT; mt += 2) {
        const int p0 = mt * 16 + ln;
        const unsigned pp = tab[p0];
        const int fi = pp & 0xff, fj = pp >> 8;

        // A[m=ln][k=qd*8+j] = emb[fi][k] * emb[fj][k], two K-halves
        half8 a0 = *(const half8*)(&emb[fi][qd * 8])      * *(const half8*)(&emb[fj][qd * 8]);
        half8 a1 = *(const half8*)(&emb[fi][32 + qd * 8]) * *(const half8*)(&emb[fj][32 + qd * 8]);

        float lg[4] = {0.f, 0.f, 0.f, 0.f};
        #pragma unroll
        for (int nt = 0; nt < 4; ++nt) {
            f32x4 acc = {0.f, 0.f, 0.f, 0.f};
            acc = __builtin_amdgcn_mfma_f32_16x16x32_f16(a0, bfr[nt][0], acc, 0, 0, 0);
            acc = __builtin_amdgcn_mfma_f32_16x16x32_f16(a1, bfr[nt][1], acc, 0, 0, 0);
            // C layout: col = ln (a), row = qd*4 + reg (pair)
            #pragma unroll
            for (int rr = 0; rr < 4; ++rr)
                lg[rr] = fmaf(fmaxf(acc[rr] + b1v[nt], 0.f), w2v[nt], lg[rr]);
        }
        #pragma unroll
        for (int off = 1; off <= 8; off <<= 1) {
            #pragma unroll
            for (int rr = 0; rr < 4; ++rr) lg[rr] += __shfl_xor(lg[rr], off, 64);
        }
        if (ln == 0) {
            const int pr = mt * 16 + qd * 4;
            float4 st;
            st.x = (pr + 0 < NP) ? lg[0] : -INFINITY;
            st.y = (pr + 1 < NP) ? lg[1] : -INFINITY;
            st.z = (pr + 2 < NP) ? lg[2] : -INFINITY;
            st.w = (pr + 3 < NP) ? lg[3] : -INFINITY;
            *(float4*)(&scores[pr]) = st;
        }
    }

    __syncthreads();   // logits visible

    // ---- softmax over 336 (pads -inf). Both waves compute redundantly,
    //      write disjoint chunks (wave0: k=0..2, wave1: k=3..5). ----
    float v[6];
    #pragma unroll
    for (int k = 0; k < 6; ++k) {
        int p = lane + (k << 6);
        v[k] = (p < NPP) ? scores[p] : -INFINITY;
    }
    float m = v[0];
    #pragma unroll
    for (int k = 1; k < 6; ++k) m = fmaxf(m, v[k]);
    #pragma unroll
    for (int off = 32; off >= 1; off >>= 1) m = fmaxf(m, __shfl_xor(m, off, 64));
    float e[6], esum = 0.f;
    #pragma unroll
    for (int k = 0; k < 6; ++k) { e[k] = __expf(v[k] - m); esum += e[k]; }
    #pragma unroll
    for (int off = 32; off >= 1; off >>= 1) esum += __shfl_xor(esum, off, 64);
    const float rinv = 1.0f / esum;
    __syncthreads();   // all raw-logit reads done before overwrite
    #pragma unroll
    for (int k = 0; k < 6; ++k) {
        if ((k >= wave * 3) && (k < wave * 3 + 3)) {
            int p = lane + (k << 6);
            if (p < NPP) scores[p] = e[k] * rinv;
        }
    }

    __syncthreads();   // normalized scores visible

    // ---- phase 3: att_out[d] = sum_p s_p * emb_i[d]*emb_j[d], packed f16.
    //      16 pairs/iter across both waves, 21 iters. ----
    const int dg  = lane & 7;                    // dim group: d = dg*8 .. dg*8+7
    const int sub = (wave << 3) + (lane >> 3);   // pair sub 0..15
    half8 acc8 = { (_Float16)0.f, (_Float16)0.f, (_Float16)0.f, (_Float16)0.f,
                   (_Float16)0.f, (_Float16)0.f, (_Float16)0.f, (_Float16)0.f };
    for (int it = 0; it < NPP / 16; ++it) {   // pads have score 0
        const int p = it * 16 + sub;
        const float s = scores[p];
        const unsigned pp = tab[p];
        const int fi = pp & 0xff, fj = pp >> 8;
        const _Float16 sh = (_Float16)s;
        half8 sv = { sh, sh, sh, sh, sh, sh, sh, sh };
        half8 x = *(const half8*)(&emb[fi][dg * 8]) * *(const half8*)(&emb[fj][dg * 8]);
        acc8 += sv * x;                       // v_pk_fma_f16
    }
    // reduce over this wave's sub lanes (bits 3..5)
    float av[8];
    #pragma unroll
    for (int i = 0; i < 8; ++i) av[i] = (float)acc8[i];
    #pragma unroll
    for (int off = 8; off <= 32; off <<= 1) {
        #pragma unroll
        for (int i = 0; i < 8; ++i) av[i] += __shfl_xor(av[i], off, 64);
    }
    if (lane < 8) {
        *(float4*)(&partial[wave][lane * 8])     = make_float4(av[0], av[1], av[2], av[3]);
        *(float4*)(&partial[wave][lane * 8 + 4]) = make_float4(av[4], av[5], av[6], av[7]);
    }
    __syncthreads();

    // ---- final: combine wave partials, project with p, add linear ----
    if (wave == 0 && lane < 8) {
        float4 s0 = *(const float4*)(&partial[0][lane * 8]);
        float4 s1 = *(const float4*)(&partial[0][lane * 8 + 4]);
        float4 t0 = *(const float4*)(&partial[1][lane * 8]);
        float4 t1 = *(const float4*)(&partial[1][lane * 8 + 4]);
        float4 pa = *(const float4*)(proj + lane * 8);
        float4 pb = *(const float4*)(proj + lane * 8 + 4);
        float part = (s0.x + t0.x) * pa.x + (s0.y + t0.y) * pa.y
                   + (s0.z + t0.z) * pa.z + (s0.w + t0.w) * pa.w
                   + (s1.x + t1.x) * pb.x + (s1.y + t1.y) * pb.y
                   + (s1.z + t1.z) * pb.z + (s1.w + t1.w) * pb.w;
        #pragma unroll
        for (int off = 1; off <= 4; off <<= 1) part += __shfl_xor(part, off, 64);
        if (lane == 0) out[r] = lin + part;
    }
}

extern "C" void kernel_launch(void* const* d_in, const int* in_sizes, int n_in,
                              void* d_out, int out_size, void* d_ws, size_t ws_size,
                              hipStream_t stream) {
    const int*   sparse = (const int*)  d_in[0];
    const float* dense  = (const float*)d_in[1];
    const float* etab   = (const float*)d_in[2];
    const float* ltab   = (const float*)d_in[3];
    const float* wdense = (const float*)d_in[4];
    const float* bias   = (const float*)d_in[5];
    const float* W1     = (const float*)d_in[6];
    const float* b1     = (const float*)d_in[7];
    const float* w2     = (const float*)d_in[8];
    const float* proj   = (const float*)d_in[9];
    float* outp = (float*)d_out;

    _Float16*       w1t = (_Float16*)d_ws;                          // 8192 B
    unsigned short* tab = (unsigned short*)((char*)d_ws + 8192);    //  672 B

    const int B = in_sizes[0] / NF;

    prep_kernel<<<dim3(1), dim3(256), 0, stream>>>(W1, w1t, tab);
    afm_kernel<<<dim3(B), dim3(BLOCK), 0, stream>>>(
        sparse, dense, etab, ltab, wdense, bias, b1, w2, proj, w1t, tab, outp);
    (void)n_in; (void)out_size; (void)ws_size;
}

// Round 6
// 125.529 us; speedup vs baseline: 1.3416x; 1.0771x over previous
//
#include <hip/hip_runtime.h>
#include <math.h>

// AFM forward: out[b] = linear(b) + softmax-weighted pair-interaction projection.
// B=4096, F=26, d=64, P=325 pairs, af=64.
//
// R6: DS-pipe diet. R5 post-mortem: wall is the LDS/DS pipe (~60-70% busy;
// shuffles are ds_bpermute), not VALU/MFMA/latency. Changes:
//  - MFMA operand swap: D[af][pair] (A=W1^T frag, B=x frag -- same registers,
//    swapped args). Logit reduce over af = in-lane over 4 regs + 2 shuffles,
//    vs 16 shuffles per m-tile. acc initialized with b1 (saves 16 adds/mt).
//  - Phase-3 cross-lane reduce in packed f16 (12 bpermutes vs 24); partials
//    collapse to 2 scalars (no [2][64] LDS roundtrip).
//  - Softmax + staging LDS traffic vectorized to b128.

#define NF 26
#define NP 325
#define NPP 336          // padded to 21 m-tiles of 16
#define NMT 21
#define ED 64
#define AF 64
#define NDENSE 13
#define BLOCK 128        // 2 waves, one row per block
#define ESTRIDE 72       // f16 elems per emb row: 144 B (16B-aligned)

typedef __attribute__((ext_vector_type(8))) _Float16 half8;
typedef __attribute__((ext_vector_type(4))) float f32x4;

__device__ __forceinline__ half8 shfl_xor_h8(half8 v, int off) {
    union { half8 h; int i[4]; } u; u.h = v;
    #pragma unroll
    for (int k = 0; k < 4; ++k) u.i[k] = __shfl_xor(u.i[k], off, 64);
    return u.h;
}

__global__ void prep_kernel(const float* __restrict__ W1,
                            _Float16* __restrict__ w1t,        // [64][64] = W1^T, f16
                            unsigned short* __restrict__ tab)  // [336] i | j<<8
{
    int t = threadIdx.x;
    for (int idx = t; idx < ED * AF; idx += 256) {
        int d = idx >> 6, a = idx & 63;       // W1 is [d][a]
        w1t[a * ED + d] = (_Float16)W1[idx];
    }
    if (t < NPP) {
        unsigned short v = 0;
        if (t < NP) {
            int rem = t, i = 0;
            while (rem >= NF - 1 - i) { rem -= NF - 1 - i; ++i; }
            v = (unsigned short)(i | ((i + 1 + rem) << 8));
        }
        tab[t] = v;
    }
}

__global__ __launch_bounds__(BLOCK, 4)
void afm_kernel(const int*   __restrict__ sparse,   // [B,26]
                const float* __restrict__ dense,    // [B,13]
                const float* __restrict__ etab,     // [V,64]
                const float* __restrict__ ltab,     // [V]
                const float* __restrict__ wdense,   // [13]
                const float* __restrict__ bias,     // [1]
                const float* __restrict__ b1,       // [64]
                const float* __restrict__ w2,       // [64]
                const float* __restrict__ proj,     // [64]
                const _Float16* __restrict__ w1t,   // [64][64] f16 (a-major)
                const unsigned short* __restrict__ tab, // [336]
                float*       __restrict__ out)      // [B]
{
    const int t    = threadIdx.x;
    const int wave = t >> 6;
    const int lane = t & 63;
    const int qd   = lane >> 4;     // quad 0..3
    const int ln   = lane & 15;
    const int r    = blockIdx.x;    // this block's batch row

    __shared__ alignas(16) _Float16 emb[NF][ESTRIDE];   // 3744 B
    __shared__ alignas(16) float    scores[NPP];        // 1344 B
    __shared__ float pw[2];

    // ---- W1^T fragment preload (A-operand after swap): lane holds
    //      w1t[af = nt*16+ln][k = kh*32 + qd*8 + j]  (8 KB, L2-hot) ----
    half8 bfr[4][2];
    #pragma unroll
    for (int nt = 0; nt < 4; ++nt)
        #pragma unroll
        for (int kh = 0; kh < 2; ++kh)
            bfr[nt][kh] = *(const half8*)(w1t + (nt * 16 + ln) * ED + kh * 32 + qd * 8);

    // b1/w2 for af = nt*16 + qd*4 + rr  (C-row mapping after swap)
    float4 b1v4[4], w2v4[4];
    #pragma unroll
    for (int nt = 0; nt < 4; ++nt) {
        b1v4[nt] = *(const float4*)(b1 + nt * 16 + qd * 4);
        w2v4[nt] = *(const float4*)(w2 + nt * 16 + qd * 4);
    }

    // ---- stage this row's 26 embeddings into LDS as f16, b128 writes ----
    const int* __restrict__ srow = sparse + r * NF;
    for (int task = t; task < NF * 8; task += BLOCK) {
        int f = task >> 3, c = task & 7;                 // 8-half chunk
        const float* src = etab + (size_t)srow[f] * ED + c * 8;
        float4 v0 = *(const float4*)(src);
        float4 v1 = *(const float4*)(src + 4);
        half8 h = { (_Float16)v0.x, (_Float16)v0.y, (_Float16)v0.z, (_Float16)v0.w,
                    (_Float16)v1.x, (_Float16)v1.y, (_Float16)v1.z, (_Float16)v1.w };
        *(half8*)(&emb[f][c * 8]) = h;
    }

    // ---- linear part (wave 0 registers only) ----
    float lin = 0.f;
    if (wave == 0) {
        if (lane < NF) {
            lin = ltab[srow[lane]];
        } else if (lane >= 32 && lane < 32 + NDENSE) {
            int k = lane - 32;
            lin = dense[r * NDENSE + k] * wdense[k];
        }
        #pragma unroll
        for (int off = 32; off >= 1; off >>= 1) lin += __shfl_xor(lin, off, 64);
        lin += bias[0];
    }

    __syncthreads();   // emb visible

    // ---- phase 1: logits via operand-swapped MFMA. D[m=af][n=pair]:
    //      C layout col = ln = pair, row = qd*4+reg = af (within nt*16). ----
    for (int mt = wave; mt < NMT; mt += 2) {
        const int p0 = mt * 16 + ln;
        const unsigned pp = tab[p0];
        const int fi = pp & 0xff, fj = pp >> 8;

        // B-frag: x[pair=ln][k=kh*32+qd*8+j]
        half8 x0 = *(const half8*)(&emb[fi][qd * 8])      * *(const half8*)(&emb[fj][qd * 8]);
        half8 x1 = *(const half8*)(&emb[fi][32 + qd * 8]) * *(const half8*)(&emb[fj][32 + qd * 8]);

        float lg = 0.f;
        #pragma unroll
        for (int nt = 0; nt < 4; ++nt) {
            f32x4 acc = { b1v4[nt].x, b1v4[nt].y, b1v4[nt].z, b1v4[nt].w };
            acc = __builtin_amdgcn_mfma_f32_16x16x32_f16(bfr[nt][0], x0, acc, 0, 0, 0);
            acc = __builtin_amdgcn_mfma_f32_16x16x32_f16(bfr[nt][1], x1, acc, 0, 0, 0);
            lg = fmaf(fmaxf(acc[0], 0.f), w2v4[nt].x, lg);
            lg = fmaf(fmaxf(acc[1], 0.f), w2v4[nt].y, lg);
            lg = fmaf(fmaxf(acc[2], 0.f), w2v4[nt].z, lg);
            lg = fmaf(fmaxf(acc[3], 0.f), w2v4[nt].w, lg);
        }
        // sum over the 4 qd groups (lanes ln, ln+16, ln+32, ln+48)
        lg += __shfl_xor(lg, 16, 64);
        lg += __shfl_xor(lg, 32, 64);
        if (qd == 0) scores[p0] = (p0 < NP) ? lg : -INFINITY;
    }

    __syncthreads();   // logits visible

    // ---- softmax over 336 (pads -inf), float4 traffic. Both waves compute
    //      redundantly; disjoint write ranges. 84 float4 chunks. ----
    float4 v0 = *(const float4*)(&scores[lane * 4]);                 // chunks 0..63
    float4 v1 = make_float4(-INFINITY, -INFINITY, -INFINITY, -INFINITY);
    if (lane < NPP / 4 - 64) v1 = *(const float4*)(&scores[(lane + 64) * 4]);

    float m = fmaxf(fmaxf(fmaxf(v0.x, v0.y), fmaxf(v0.z, v0.w)),
                    fmaxf(fmaxf(v1.x, v1.y), fmaxf(v1.z, v1.w)));
    #pragma unroll
    for (int off = 32; off >= 1; off >>= 1) m = fmaxf(m, __shfl_xor(m, off, 64));
    float4 e0, e1;
    e0.x = __expf(v0.x - m); e0.y = __expf(v0.y - m);
    e0.z = __expf(v0.z - m); e0.w = __expf(v0.w - m);
    e1.x = __expf(v1.x - m); e1.y = __expf(v1.y - m);
    e1.z = __expf(v1.z - m); e1.w = __expf(v1.w - m);
    float esum = e0.x + e0.y + e0.z + e0.w + e1.x + e1.y + e1.z + e1.w;
    #pragma unroll
    for (int off = 32; off >= 1; off >>= 1) esum += __shfl_xor(esum, off, 64);
    const float rinv = 1.0f / esum;

    __syncthreads();   // all raw-logit reads done before overwrite
    if (wave == 0) {
        e0.x *= rinv; e0.y *= rinv; e0.z *= rinv; e0.w *= rinv;
        *(float4*)(&scores[lane * 4]) = e0;
    } else if (lane < NPP / 4 - 64) {
        e1.x *= rinv; e1.y *= rinv; e1.z *= rinv; e1.w *= rinv;
        *(float4*)(&scores[(lane + 64) * 4]) = e1;
    }

    __syncthreads();   // normalized scores visible

    // ---- phase 3: att_out[d] = sum_p s_p * emb_i[d]*emb_j[d], packed f16.
    //      16 pair-subs per iter across both waves, 21 iters. ----
    const int dg  = lane & 7;                    // dim group: d = dg*8 .. dg*8+7
    const int sub = (wave << 3) + (lane >> 3);   // pair sub 0..15
    half8 acc8 = { (_Float16)0.f, (_Float16)0.f, (_Float16)0.f, (_Float16)0.f,
                   (_Float16)0.f, (_Float16)0.f, (_Float16)0.f, (_Float16)0.f };
    for (int it = 0; it < NPP / 16; ++it) {      // pads have score 0
        const int p = it * 16 + sub;
        const float s = scores[p];
        const unsigned pp = tab[p];
        const int fi = pp & 0xff, fj = pp >> 8;
        const _Float16 sh = (_Float16)s;
        half8 sv = { sh, sh, sh, sh, sh, sh, sh, sh };
        half8 x = *(const half8*)(&emb[fi][dg * 8]) * *(const half8*)(&emb[fj][dg * 8]);
        acc8 += sv * x;                           // v_pk_fma_f16
    }
    // packed reduce over sub lanes (bits 3..5): 12 bpermutes
    acc8 += shfl_xor_h8(acc8, 8);
    acc8 += shfl_xor_h8(acc8, 16);
    acc8 += shfl_xor_h8(acc8, 32);
    // dot with proj for this dg, then reduce over dg (bits 0..2)
    float4 pa = *(const float4*)(proj + dg * 8);
    float4 pb = *(const float4*)(proj + dg * 8 + 4);
    float part = (float)acc8[0] * pa.x + (float)acc8[1] * pa.y
               + (float)acc8[2] * pa.z + (float)acc8[3] * pa.w
               + (float)acc8[4] * pb.x + (float)acc8[5] * pb.y
               + (float)acc8[6] * pb.z + (float)acc8[7] * pb.w;
    #pragma unroll
    for (int off = 1; off <= 4; off <<= 1) part += __shfl_xor(part, off, 64);
    if (lane == 0) pw[wave] = part;

    __syncthreads();
    if (t == 0) out[r] = lin + pw[0] + pw[1];
}

extern "C" void kernel_launch(void* const* d_in, const int* in_sizes, int n_in,
                              void* d_out, int out_size, void* d_ws, size_t ws_size,
                              hipStream_t stream) {
    const int*   sparse = (const int*)  d_in[0];
    const float* dense  = (const float*)d_in[1];
    const float* etab   = (const float*)d_in[2];
    const float* ltab   = (const float*)d_in[3];
    const float* wdense = (const float*)d_in[4];
    const float* bias   = (const float*)d_in[5];
    const float* W1     = (const float*)d_in[6];
    const float* b1     = (const float*)d_in[7];
    const float* w2     = (const float*)d_in[8];
    const float* proj   = (const float*)d_in[9];
    float* outp = (float*)d_out;

    _Float16*       w1t = (_Float16*)d_ws;                          // 8192 B
    unsigned short* tab = (unsigned short*)((char*)d_ws + 8192);    //  672 B

    const int B = in_sizes[0] / NF;

    prep_kernel<<<dim3(1), dim3(256), 0, stream>>>(W1, w1t, tab);
    afm_kernel<<<dim3(B), dim3(BLOCK), 0, stream>>>(
        sparse, dense, etab, ltab, wdense, bias, b1, w2, proj, w1t, tab, outp);
    (void)n_in; (void)out_size; (void)ws_size;
}

// Round 7
// 116.217 us; speedup vs baseline: 1.4491x; 1.0801x over previous
//
#include <hip/hip_runtime.h>
#include <math.h>

// AFM forward: out[b] = linear(b) + softmax-weighted pair-interaction projection.
// B=4096, F=26, d=64, P=325 pairs, af=64.
//
// R7: online-softmax fusion. R6 post-mortem: no pipe >40% busy; wave lifetime
// ~35K cyc vs ~10K of issue -> dependency-stall bound across serial phases.
// Fix: fold softmax + phase-3 into the phase-1 m-tile loop (flash idiom).
// Each lane keeps running (m, l) and a 16-dim f16 accumulator acc += e*x,
// rescaled by alpha = exp(m_old - m_new); x (pair products) are already in
// registers from the MFMA B-frag build. Deletes phase-3's 42-iteration LDS
// loop, the scores[] LDS array, both softmax LDS round-trips, and 2 syncs.
// 1 row/wave, 4 waves/block, no block barriers (wave-local wsync only).

#define NF 26
#define NP 325
#define NMT 21           // 21 m-tiles of 16 pairs (336, pads -> -inf)
#define ED 64
#define AF 64
#define NDENSE 13
#define WPB 4            // waves (rows) per block
#define BLOCK (WPB * 64)
#define ESTRIDE 72       // f16 elems per emb row: 144 B (16B-aligned rows)

typedef __attribute__((ext_vector_type(8))) _Float16 half8;
typedef __attribute__((ext_vector_type(4))) float f32x4;

__device__ __forceinline__ void wsync() {
    // wave-local producer->consumer ordering through LDS (verified R3-R6).
    __builtin_amdgcn_fence(__ATOMIC_ACQ_REL, "workgroup");
    __builtin_amdgcn_wave_barrier();
}

__global__ void prep_kernel(const float* __restrict__ W1,
                            _Float16* __restrict__ w1t,        // [64][64] = W1^T, f16
                            unsigned short* __restrict__ tab)  // [336] i | j<<8
{
    int t = threadIdx.x;
    for (int idx = t; idx < ED * AF; idx += 256) {
        int d = idx >> 6, a = idx & 63;       // W1 is [d][a]
        w1t[a * ED + d] = (_Float16)W1[idx];
    }
    if (t < NMT * 16) {
        unsigned short v = 0;
        if (t < NP) {
            int rem = t, i = 0;
            while (rem >= NF - 1 - i) { rem -= NF - 1 - i; ++i; }
            v = (unsigned short)(i | ((i + 1 + rem) << 8));
        }
        tab[t] = v;
    }
}

__global__ __launch_bounds__(BLOCK, 4)   // VGPR cap 128 (R4 lesson: never cap below live set)
void afm_kernel(const int*   __restrict__ sparse,   // [B,26]
                const float* __restrict__ dense,    // [B,13]
                const float* __restrict__ etab,     // [V,64]
                const float* __restrict__ ltab,     // [V]
                const float* __restrict__ wdense,   // [13]
                const float* __restrict__ bias,     // [1]
                const float* __restrict__ b1,       // [64]
                const float* __restrict__ w2,       // [64]
                const float* __restrict__ proj,     // [64]
                const _Float16* __restrict__ w1t,   // [64][64] f16 (a-major)
                const unsigned short* __restrict__ tab, // [336]
                float*       __restrict__ out,      // [B]
                int B)
{
    const int t    = threadIdx.x;
    const int wave = t >> 6;
    const int lane = t & 63;
    const int qd   = lane >> 4;     // quad 0..3
    const int ln   = lane & 15;

    const int r = blockIdx.x * WPB + wave;   // this wave's batch row
    if (r >= B) return;                      // safe: no block barriers

    __shared__ alignas(16) _Float16 emb_all[WPB][NF][ESTRIDE];  // 14976 B
    _Float16 (* __restrict__ emb)[ESTRIDE] = emb_all[wave];

    // ---- W1^T A-operand fragments (L2-hot 8 KB):
    //      bfr[nt][kh] = w1t[af = nt*16+ln][k = kh*32 + qd*8 + j] ----
    half8 bfr[4][2];
    #pragma unroll
    for (int nt = 0; nt < 4; ++nt)
        #pragma unroll
        for (int kh = 0; kh < 2; ++kh)
            bfr[nt][kh] = *(const half8*)(w1t + (nt * 16 + ln) * ED + kh * 32 + qd * 8);

    // b1/w2 for af = nt*16 + qd*4 + rr  (C-row mapping)
    float4 b1v4[4], w2v4[4];
    #pragma unroll
    for (int nt = 0; nt < 4; ++nt) {
        b1v4[nt] = *(const float4*)(b1 + nt * 16 + qd * 4);
        w2v4[nt] = *(const float4*)(w2 + nt * 16 + qd * 4);
    }

    // ---- stage this row's 26 embeddings into LDS as f16, b128 writes ----
    const int* __restrict__ srow = sparse + r * NF;
    for (int task = lane; task < NF * 8; task += 64) {
        int f = task >> 3, c = task & 7;                 // 8-half chunk
        const float* src = etab + (size_t)srow[f] * ED + c * 8;
        float4 v0 = *(const float4*)(src);
        float4 v1 = *(const float4*)(src + 4);
        half8 h = { (_Float16)v0.x, (_Float16)v0.y, (_Float16)v0.z, (_Float16)v0.w,
                    (_Float16)v1.x, (_Float16)v1.y, (_Float16)v1.z, (_Float16)v1.w };
        *(half8*)(&emb[f][c * 8]) = h;
    }

    // ---- linear part (wave-local registers) ----
    float lin = 0.f;
    if (lane < NF) {
        lin = ltab[srow[lane]];
    } else if (lane >= 32 && lane < 32 + NDENSE) {
        int k = lane - 32;
        lin = dense[r * NDENSE + k] * wdense[k];
    }
    #pragma unroll
    for (int off = 32; off >= 1; off >>= 1) lin += __shfl_xor(lin, off, 64);
    lin += bias[0];

    wsync();   // emb visible to all lanes of this wave

    // ---- fused main loop: logits via operand-swapped MFMA + online softmax.
    //      Lane state: m (running max), l (running denom), acc0/acc1 (f16,
    //      dims qd*8..+7 and 32+qd*8..+7) accumulating e_p * x_p[d]. ----
    float m = -INFINITY, l = 0.f;
    half8 acc0 = { (_Float16)0.f, (_Float16)0.f, (_Float16)0.f, (_Float16)0.f,
                   (_Float16)0.f, (_Float16)0.f, (_Float16)0.f, (_Float16)0.f };
    half8 acc1 = acc0;

    // depth-1 pipeline: prefetch next mt's tab + emb fragments
    unsigned pp = tab[ln];                       // mt=0
    int fi = pp & 0xff, fj = pp >> 8;
    half8 ei0 = *(const half8*)(&emb[fi][qd * 8]);
    half8 ei1 = *(const half8*)(&emb[fi][32 + qd * 8]);
    half8 ej0 = *(const half8*)(&emb[fj][qd * 8]);
    half8 ej1 = *(const half8*)(&emb[fj][32 + qd * 8]);

    for (int mt = 0; mt < NMT; ++mt) {
        half8 x0 = ei0 * ej0;                    // pair product, in registers
        half8 x1 = ei1 * ej1;

        if (mt + 1 < NMT) {                      // issue next tile's loads now
            unsigned np = tab[(mt + 1) * 16 + ln];
            int nfi = np & 0xff, nfj = np >> 8;
            ei0 = *(const half8*)(&emb[nfi][qd * 8]);
            ei1 = *(const half8*)(&emb[nfi][32 + qd * 8]);
            ej0 = *(const half8*)(&emb[nfj][qd * 8]);
            ej1 = *(const half8*)(&emb[nfj][32 + qd * 8]);
        }

        // logits: D[m=af][n=pair=ln]; C rows = qd*4+reg = af within nt*16
        float lg = 0.f;
        #pragma unroll
        for (int nt = 0; nt < 4; ++nt) {
            f32x4 acc = { b1v4[nt].x, b1v4[nt].y, b1v4[nt].z, b1v4[nt].w };
            acc = __builtin_amdgcn_mfma_f32_16x16x32_f16(bfr[nt][0], x0, acc, 0, 0, 0);
            acc = __builtin_amdgcn_mfma_f32_16x16x32_f16(bfr[nt][1], x1, acc, 0, 0, 0);
            lg = fmaf(fmaxf(acc[0], 0.f), w2v4[nt].x, lg);
            lg = fmaf(fmaxf(acc[1], 0.f), w2v4[nt].y, lg);
            lg = fmaf(fmaxf(acc[2], 0.f), w2v4[nt].z, lg);
            lg = fmaf(fmaxf(acc[3], 0.f), w2v4[nt].w, lg);
        }
        // sum over the 4 qd groups -> full 64-af logit, replicated across qd
        lg += __shfl_xor(lg, 16, 64);
        lg += __shfl_xor(lg, 32, 64);

        const int p0 = mt * 16 + ln;
        if (p0 >= NP) lg = -INFINITY;            // pad pairs contribute 0

        // online-softmax update (per-lane running state)
        float mn    = fmaxf(m, lg);
        float alpha = __expf(m - mn);            // m=-inf first iter -> 0
        float e     = __expf(lg - mn);           // lg=-inf pad -> 0
        l = l * alpha + e;
        m = mn;
        _Float16 ah = (_Float16)alpha, eh = (_Float16)e;
        half8 a8 = { ah, ah, ah, ah, ah, ah, ah, ah };
        half8 e8 = { eh, eh, eh, eh, eh, eh, eh, eh };
        acc0 = acc0 * a8 + x0 * e8;              // v_pk_fma_f16
        acc1 = acc1 * a8 + x1 * e8;
    }

    // ---- merge: lanes sharing qd (ln = bits 0..3) cover all 336 pairs ----
    float mg = m;
    #pragma unroll
    for (int off = 1; off <= 8; off <<= 1) mg = fmaxf(mg, __shfl_xor(mg, off, 64));
    const float fac = __expf(m - mg);            // per-lane rescale to global max
    float lsum = l * fac;
    #pragma unroll
    for (int off = 1; off <= 8; off <<= 1) lsum += __shfl_xor(lsum, off, 64);
    // lsum now = global softmax denominator, identical across qd groups

    // proj-dot in-lane (dims qd*8..+7 and 32+qd*8..+7), scaled by fac
    float4 pa = *(const float4*)(proj + qd * 8);
    float4 pb = *(const float4*)(proj + qd * 8 + 4);
    float4 pc = *(const float4*)(proj + 32 + qd * 8);
    float4 pd = *(const float4*)(proj + 32 + qd * 8 + 4);
    float rr = (float)acc0[0] * pa.x + (float)acc0[1] * pa.y
             + (float)acc0[2] * pa.z + (float)acc0[3] * pa.w
             + (float)acc0[4] * pb.x + (float)acc0[5] * pb.y
             + (float)acc0[6] * pb.z + (float)acc0[7] * pb.w
             + (float)acc1[0] * pc.x + (float)acc1[1] * pc.y
             + (float)acc1[2] * pc.z + (float)acc1[3] * pc.w
             + (float)acc1[4] * pd.x + (float)acc1[5] * pd.y
             + (float)acc1[6] * pd.z + (float)acc1[7] * pd.w;
    rr *= fac;
    // sum over ln (pairs) and qd (dim chunks): all 6 lane bits
    #pragma unroll
    for (int off = 1; off <= 32; off <<= 1) rr += __shfl_xor(rr, off, 64);

    if (lane == 0) out[r] = lin + rr / lsum;
}

extern "C" void kernel_launch(void* const* d_in, const int* in_sizes, int n_in,
                              void* d_out, int out_size, void* d_ws, size_t ws_size,
                              hipStream_t stream) {
    const int*   sparse = (const int*)  d_in[0];
    const float* dense  = (const float*)d_in[1];
    const float* etab   = (const float*)d_in[2];
    const float* ltab   = (const float*)d_in[3];
    const float* wdense = (const float*)d_in[4];
    const float* bias   = (const float*)d_in[5];
    const float* W1     = (const float*)d_in[6];
    const float* b1     = (const float*)d_in[7];
    const float* w2     = (const float*)d_in[8];
    const float* proj   = (const float*)d_in[9];
    float* outp = (float*)d_out;

    _Float16*       w1t = (_Float16*)d_ws;                          // 8192 B
    unsigned short* tab = (unsigned short*)((char*)d_ws + 8192);    //  672 B

    const int B = in_sizes[0] / NF;

    prep_kernel<<<dim3(1), dim3(256), 0, stream>>>(W1, w1t, tab);
    afm_kernel<<<dim3((B + WPB - 1) / WPB), dim3(BLOCK), 0, stream>>>(
        sparse, dense, etab, ltab, wdense, bias, b1, w2, proj, w1t, tab, outp, B);
    (void)n_in; (void)out_size; (void)ws_size;
}